// Round 6
// baseline (9049.380 us; speedup 1.0000x reference)
//
#include <hip/hip_runtime.h>

// Shapes: VOCAB=128, EMBED=512, HIDDEN=1024, B=64, T=512. Inputs fp32, x int32.
// ws layout (bytes):
//   tableV : [128 vocab][4096 C] fp16   @ 0         (1 MB)   xin0+bias, block-local col order
//   fcwT   : [1024 k][128 v] fp16       @ 1048576   (256 KB)
//   hcat   : [2 bufs][64 b][2048 k] f16 @ 1310720   (512 KB) k<1024: h1, k>=1024: h2
//   cnt    : [512 it][112 words] u32    @ 1835008   (224 KB) barrier state
//   h2s    : [512 t][64 b][1024 u] f16  @ 2064640   (64 MB)
//   ext    : census[8]+pre[2] u32       @ 2064384   (256 B)  total 69,173,504 B
//
// Column mapping: global col C = blk*16 + g*4 + j  <->  gate-row g*1024 + blk*4 + j.
//
// Cross-XCD protocol: all cross-block stores are agent-scope relaxed atomics
// (write-through at L3 coherence point, never dirty in L2). Barrier per iter:
//   vmcnt drain -> per-XCD arrive -> every CU: L1 flash-inv; LAST block of
//   the XCD (count from startup census, robust to uneven dispatch): ONE
//   buffer_inv sc1 per XCD per iter (rounds 3/4 did 32/XCD = ~14 us/iter of
//   serialized L2 cache ops) + vmcnt drain BEFORE group-arrive, so release
//   implies all XCD invs completed -> group counters -> root -> release
//   flags -> spin. Safety: stale write-buffer lines date from 2 iters ago;
//   nobody loads write-buffer addresses between inv and release (spins are
//   L2-bypassing atomics, parked waves issue nothing, pre-arrive blocks only
//   re-fill current-data lines: hr / x / tableV).
// cnt words per iter (112): xcd[k]@k*4, group[g]@32+g*4, root@64, rel[g]@68+g*4.

typedef _Float16 v8h __attribute__((ext_vector_type(8)));
typedef float v4f __attribute__((ext_vector_type(4)));
typedef _Float16 h2v __attribute__((ext_vector_type(2)));

__device__ __forceinline__ float sigf(float x) {
  return 1.0f / (1.0f + __expf(-x));
}

// ---------------------------------------------------------------- prep ----
__global__ __launch_bounds__(256) void prep_kernel(
    const float* __restrict__ emb, const float* __restrict__ w_ih0,
    const float* __restrict__ b_ih0, const float* __restrict__ b_hh0,
    const float* __restrict__ fc_w, _Float16* __restrict__ tableV,
    _Float16* __restrict__ fcwT, unsigned* __restrict__ zbuf,
    unsigned* __restrict__ cnt, unsigned* __restrict__ ext) {
  const int blk = blockIdx.x, tid = threadIdx.x;
  if (blk < 2048) {
    // tableV[v][C] = emb[v]·w_ih0[row(C)] + b_ih0[row] + b_hh0[row]
    const int C = blk * 2 + (tid >> 7);
    const int v = tid & 127;
    const int row = ((C >> 2) & 3) * 1024 + (C >> 4) * 4 + (C & 3);
    float acc = b_ih0[row] + b_hh0[row];
    const float* er = emb + v * 512;
    const float* wr = w_ih0 + row * 512;
#pragma unroll 4
    for (int k = 0; k < 512; ++k) acc = fmaf(er[k], wr[k], acc);
    tableV[v * 4096 + C] = (_Float16)acc;
  } else if (blk < 2560) {
    const int idx = (blk - 2048) * 256 + tid;   // [0, 131072)
    const int v = idx & 127, k = idx >> 7;
    fcwT[k * 128 + v] = (_Float16)fc_w[v * 1024 + k];
  } else if (blk < 2592) {
    // zero hcat (both ping-pong buffers): 131072 dwords over 32 blocks
    const int idx = (blk - 2560) * 256 + tid;
#pragma unroll
    for (int q = 0; q < 16; ++q) zbuf[idx * 16 + q] = 0u;
  } else {
    // zero barrier state (57344 words) + census/pre region (64 words)
    const int base = (blk - 2592) * 256 + tid;
    for (int i = base; i < 57344; i += 8192) cnt[i] = 0u;
    if (base < 64) ext[base] = 0u;
  }
}

// ------------------------------------------------------------ recurrent ----
// 256 blocks x 768 threads (12 waves, 1 block/CU by LDS capacity). Block owns
// units u0=4*blk..u0+3 (16 gate-cols per layer). Weights LDS-resident fp16 in
// B-fragment layout [col][k] (+8 halfs pad). Skew: iteration it does layer0
// step t=it (waves 0-3) and layer1 step t=it-1 (waves 4-11, LDS-reduced).
__global__ __launch_bounds__(768, 1) void lstm_mfma(
    const int* __restrict__ x, const _Float16* __restrict__ tableV,
    const float* __restrict__ w_hh0, const float* __restrict__ w_ih1,
    const float* __restrict__ w_hh1, const float* __restrict__ b_ih1,
    const float* __restrict__ b_hh1, _Float16* __restrict__ hcat,
    _Float16* __restrict__ h2s, unsigned* __restrict__ cnt,
    unsigned* __restrict__ ext) {
  __shared__ _Float16 W0L[16][1024 + 8];   // 33 KB
  __shared__ _Float16 W1L[16][2048 + 8];   // 66 KB (k<1024: w_ih1, else w_hh1)
  __shared__ float zs[12][16][17];         // per-wave C-tile scratch, 13 KB

  const int tid = threadIdx.x, blk = blockIdx.x;
  const int w = tid >> 6, l = tid & 63;
  const int lane16 = l & 15, quad = l >> 4;
  const int u0 = blk * 4;

  // --- stage weights (once): fp32 global -> fp16 LDS ---
  for (int e = tid; e < 16 * 1024; e += 768) {
    const int n = e >> 10, k = e & 1023;
    const int row = (n >> 2) * 1024 + u0 + (n & 3);
    W0L[n][k] = (_Float16)w_hh0[row * 1024 + k];
  }
  for (int e = tid; e < 16 * 2048; e += 768) {
    const int n = e >> 11, k = e & 2047;
    const int row = (n >> 2) * 1024 + u0 + (n & 3);
    const float src = (k < 1024) ? w_ih1[row * 1024 + k]
                                 : w_hh1[row * 1024 + (k - 1024)];
    W1L[n][k] = (_Float16)src;
  }

  float bias1 = 0.0f;
  if (w >= 4 && ((w - 4) & 1) == 0) {
    const int row = (lane16 >> 2) * 1024 + u0 + (lane16 & 3);
    bias1 = b_ih1[row] + b_hh1[row];
  }

  // --- startup census: how many blocks live on MY XCD (robust election) ---
  unsigned myxcc = 0u, myN = 32u;
  if (tid == 0) {
    asm volatile("s_getreg_b32 %0, hwreg(HW_REG_XCC_ID)" : "=s"(myxcc));
    myxcc &= 7u;
    __hip_atomic_fetch_add(ext + myxcc, 1u, __ATOMIC_RELAXED,
                           __HIP_MEMORY_SCOPE_AGENT);
    // acq_rel: census add is complete before this RMW is globally visible
    const unsigned old = __hip_atomic_fetch_add(ext + 8, 1u, __ATOMIC_ACQ_REL,
                                                __HIP_MEMORY_SCOPE_AGENT);
    if (old == 255u)
      __hip_atomic_store(ext + 9, 1u, __ATOMIC_RELEASE,
                         __HIP_MEMORY_SCOPE_AGENT);
    while (__hip_atomic_load(ext + 9, __ATOMIC_RELAXED,
                             __HIP_MEMORY_SCOPE_AGENT) == 0u)
      __builtin_amdgcn_s_sleep(1);
    __builtin_amdgcn_fence(__ATOMIC_ACQUIRE, "agent");
    myN = __hip_atomic_load(ext + myxcc, __ATOMIC_RELAXED,
                            __HIP_MEMORY_SCOPE_AGENT);
  }
  __syncthreads();

  float cst = 0.0f;                        // cell state (per owner lane)
  const int eb = l >> 2, ej = l & 3;       // elementwise cell mapping

  // prefetch iteration-0 xin0 gather (tableV is constant -> safe to hoist)
  _Float16 tv[4];
  if (w < 4) {
#pragma unroll
    for (int r = 0; r < 4; ++r) {
      const int b = w * 16 + quad * 4 + r;
      tv[r] = tableV[x[b * 512] * 4096 + blk * 16 + lane16];
    }
  }

  for (int it = 0; it <= 512; ++it) {
    const _Float16* hr = hcat + (it & 1) * 131072;      // [64][2048]
    _Float16* hw = hcat + ((it + 1) & 1) * 131072;

    v4f acc = {0.0f, 0.0f, 0.0f, 0.0f};
    if (w < 4) {
      if (it < 512) {                      // layer 0, t = it
        const _Float16* ap = hr + (w * 16 + lane16) * 2048 + quad * 8;
        const _Float16* bp = &W0L[lane16][quad * 8];
#pragma unroll 8
        for (int kk = 0; kk < 32; ++kk) {
          const v8h af = *(const v8h*)(ap + kk * 32);
          const v8h bf = *(const v8h*)(bp + kk * 32);
          acc = __builtin_amdgcn_mfma_f32_16x16x32_f16(af, bf, acc, 0, 0, 0);
        }
#pragma unroll
        for (int r = 0; r < 4; ++r) acc[r] += (float)tv[r];
      }
    } else {
      if (it >= 1) {                       // layer 1, t = it-1
        const int ww = w - 4, q = ww >> 1, s = ww & 1;
        if (s == 0) { acc[0] = bias1; acc[1] = bias1; acc[2] = bias1; acc[3] = bias1; }
        const _Float16* ap = hr + (q * 16 + lane16) * 2048 + s * 1024 + quad * 8;
        const _Float16* bp = &W1L[lane16][s * 1024 + quad * 8];
#pragma unroll 8
        for (int kk = 0; kk < 32; ++kk) {
          const v8h af = *(const v8h*)(ap + kk * 32);
          const v8h bf = *(const v8h*)(bp + kk * 32);
          acc = __builtin_amdgcn_mfma_f32_16x16x32_f16(af, bf, acc, 0, 0, 0);
        }
      }
    }

    // C-tile -> LDS scratch (C layout: row=quad*4+r, col=lane16)
#pragma unroll
    for (int r = 0; r < 4; ++r) zs[w][quad * 4 + r][lane16] = acc[r];
    __syncthreads();

    // elementwise: lane owns cell (b, u0+ej); gates at cols {ej,4+ej,8+ej,12+ej}
    const bool do0 = (w < 4) && (it < 512);
    const bool do1 = (w >= 4) && (((w - 4) & 1) == 0) && (it >= 1);
    if (do0 || do1) {
      float zi, zf, zg, zo;
      if (do0) {
        zi = zs[w][eb][ej];      zf = zs[w][eb][4 + ej];
        zg = zs[w][eb][8 + ej];  zo = zs[w][eb][12 + ej];
      } else {
        zi = zs[w][eb][ej] + zs[w + 1][eb][ej];
        zf = zs[w][eb][4 + ej] + zs[w + 1][eb][4 + ej];
        zg = zs[w][eb][8 + ej] + zs[w + 1][eb][8 + ej];
        zo = zs[w][eb][12 + ej] + zs[w + 1][eb][12 + ej];
      }
      const float ig = sigf(zi), fg = sigf(zf);
      const float gg = tanhf(zg), og = sigf(zo);
      cst = fg * cst + ig * gg;
      const float hv = og * tanhf(cst);

      // pack 4 units' h (consecutive lanes ej=0..3) into one 8-B coherent store
      const unsigned hu = (unsigned)__builtin_bit_cast(unsigned short, (_Float16)hv);
      const unsigned p1 = (unsigned)__shfl_xor((int)hu, 1, 64);
      const unsigned lo = (ej & 1) ? ((p1 & 0xffffu) | (hu << 16))
                                   : ((hu & 0xffffu) | (p1 << 16));
      const unsigned p2 = (unsigned)__shfl_xor((int)lo, 2, 64);
      if (ej == 0) {
        const unsigned long long val =
            (unsigned long long)lo | ((unsigned long long)p2 << 32);
        if (do0) {
          const int b = w * 16 + eb;
          __hip_atomic_store((unsigned long long*)(hw + b * 2048 + u0), val,
                             __ATOMIC_RELAXED, __HIP_MEMORY_SCOPE_AGENT);
        } else {
          const int q = (w - 4) >> 1;
          const int b = q * 16 + eb;
          __hip_atomic_store(
              (unsigned long long*)(hw + b * 2048 + 1024 + u0), val,
              __ATOMIC_RELAXED, __HIP_MEMORY_SCOPE_AGENT);
          __hip_atomic_store(
              (unsigned long long*)(h2s + ((it - 1) * 64 + b) * 1024 + u0),
              val, __ATOMIC_RELAXED, __HIP_MEMORY_SCOPE_AGENT);
        }
      }
    }

    // prefetch next iteration's xin0 gather before the barrier (overlaps it)
    if (w < 4 && it + 1 < 512) {
#pragma unroll
      for (int r = 0; r < 4; ++r) {
        const int b = w * 16 + quad * 4 + r;
        tv[r] = tableV[x[b * 512 + it + 1] * 4096 + blk * 16 + lane16];
      }
    }

    if (it < 512) {
      // ---- hierarchical multi-XCD barrier, ONE L2 inv per XCD per iter ----
      unsigned* base = cnt + it * 112;
      asm volatile("s_waitcnt vmcnt(0)" ::: "memory");  // stores+prefetch done
      __syncthreads();                                   // whole block done
      if (tid == 0) {
        const unsigned xo = __hip_atomic_fetch_add(
            base + myxcc * 4, 1u, __ATOMIC_RELAXED, __HIP_MEMORY_SCOPE_AGENT);
        // every CU: flash-invalidate own (clean, per-CU) L1
        asm volatile("buffer_inv" ::: "memory");
        if (xo == myN - 1u) {
          // last of this XCD's blocks: the XCD's single L2 invalidate;
          // confirmed complete (vmcnt) BEFORE group-arrive so the global
          // release implies all XCD invs are done.
          asm volatile("buffer_inv sc1" ::: "memory");
          asm volatile("s_waitcnt vmcnt(0)" ::: "memory");
        }
        const int g = blk & 7;
        const unsigned a = __hip_atomic_fetch_add(
            base + 32 + g * 4, 1u, __ATOMIC_RELAXED, __HIP_MEMORY_SCOPE_AGENT);
        if (a == 31u) {                   // last of this group
          const unsigned r = __hip_atomic_fetch_add(
              base + 64, 1u, __ATOMIC_RELAXED, __HIP_MEMORY_SCOPE_AGENT);
          if (r == 7u) {                  // last group overall -> release all
#pragma unroll
            for (int xx = 0; xx < 8; ++xx)
              __hip_atomic_store(base + 68 + xx * 4, 1u, __ATOMIC_RELAXED,
                                 __HIP_MEMORY_SCOPE_AGENT);
          }
        }
        while (__hip_atomic_load(base + 68 + g * 4, __ATOMIC_RELAXED,
                                 __HIP_MEMORY_SCOPE_AGENT) == 0u)
          __builtin_amdgcn_s_sleep(1);
      }
      __syncthreads();
    }
  }
}

// ---------------------------------------------------------------- FC ----
__global__ __launch_bounds__(256, 2) void fc_kernel(
    const _Float16* __restrict__ h2s, const _Float16* __restrict__ fcwT,
    const float* __restrict__ fc_b, float* __restrict__ out) {
  __shared__ float hl[16][1024];      // 64 KB
  const int tid = threadIdx.x;
  const int t = blockIdx.x >> 2, bs = blockIdx.x & 3;
  const int v = tid & 127, hh = tid >> 7;

  const h2v* hp = (const h2v*)h2s;
  for (int idx = tid; idx < 8192; idx += 256) {
    const int bl = idx >> 9, kp = idx & 511;
    const h2v pr = hp[(t * 64 + bs * 16 + bl) * 512 + kp];
    hl[bl][2 * kp] = (float)pr.x;
    hl[bl][2 * kp + 1] = (float)pr.y;
  }
  __syncthreads();

  float acc[8];
#pragma unroll
  for (int i = 0; i < 8; ++i) acc[i] = 0.0f;
  const int bl0 = hh * 8;
#pragma unroll 1
  for (int k4 = 0; k4 < 256; ++k4) {
    const int k = k4 * 4;
    const float w0 = (float)fcwT[(k + 0) * 128 + v];
    const float w1 = (float)fcwT[(k + 1) * 128 + v];
    const float w2 = (float)fcwT[(k + 2) * 128 + v];
    const float w3 = (float)fcwT[(k + 3) * 128 + v];
#pragma unroll
    for (int i = 0; i < 8; ++i) {
      const float4 hv = *(const float4*)&hl[bl0 + i][k];
      acc[i] += hv.x * w0 + hv.y * w1 + hv.z * w2 + hv.w * w3;
    }
  }
  const float bias = fc_b[v];
#pragma unroll
  for (int i = 0; i < 8; ++i) {
    const int bb = bs * 16 + bl0 + i;
    out[(bb * 512 + t) * 128 + v] = acc[i] + bias;
  }
}

// ------------------------------------------------------------- launch ----
extern "C" void kernel_launch(void* const* d_in, const int* in_sizes, int n_in,
                              void* d_out, int out_size, void* d_ws,
                              size_t ws_size, hipStream_t stream) {
  const int* x = (const int*)d_in[0];
  const float* emb = (const float*)d_in[1];
  const float* w_ih0 = (const float*)d_in[2];
  const float* w_hh0 = (const float*)d_in[3];
  const float* b_ih0 = (const float*)d_in[4];
  const float* b_hh0 = (const float*)d_in[5];
  const float* w_ih1 = (const float*)d_in[6];
  const float* w_hh1 = (const float*)d_in[7];
  const float* b_ih1 = (const float*)d_in[8];
  const float* b_hh1 = (const float*)d_in[9];
  const float* fc_w = (const float*)d_in[10];
  const float* fc_b = (const float*)d_in[11];
  float* out = (float*)d_out;

  char* ws = (char*)d_ws;
  _Float16* tableV = (_Float16*)(ws);
  _Float16* fcwT = (_Float16*)(ws + 1048576);
  _Float16* hcat = (_Float16*)(ws + 1310720);
  unsigned* cnt = (unsigned*)(ws + 1835008);
  unsigned* ext = (unsigned*)(ws + 2064384);
  _Float16* h2s = (_Float16*)(ws + 2064640);
  unsigned* zb = (unsigned*)(ws + 1310720);

  prep_kernel<<<2624, 256, 0, stream>>>(emb, w_ih0, b_ih0, b_hh0, fc_w,
                                        tableV, fcwT, zb, cnt, ext);

  const _Float16* tableVc = tableV;
  _Float16* hcata = hcat;
  _Float16* h2sa = h2s;
  unsigned* cnta = cnt;
  unsigned* exta = ext;
  void* args[] = {(void*)&x,     (void*)&tableVc, (void*)&w_hh0,
                  (void*)&w_ih1, (void*)&w_hh1,   (void*)&b_ih1,
                  (void*)&b_hh1, (void*)&hcata,   (void*)&h2sa,
                  (void*)&cnta,  (void*)&exta};
  hipLaunchCooperativeKernel(lstm_mfma, dim3(256), dim3(768), args, 0, stream);

  fc_kernel<<<2048, 256, 0, stream>>>(h2s, fcwT, fc_b, out);
}

// Round 7
// 8013.950 us; speedup vs baseline: 1.1292x; 1.1292x over previous
//
#include <hip/hip_runtime.h>

// Shapes: VOCAB=128, EMBED=512, HIDDEN=1024, B=64, T=512. Inputs fp32, x int32.
// ws layout (bytes):
//   tableV : [128 vocab][4096 C] fp16   @ 0         (1 MB)  xin0+bias
//   fcwT   : [1024 k][128 v] fp16       @ 1048576   (256 KB)
//   hcat   : [2 bufs][64 b][2048 k] f16 @ 1310720   (512 KB) k<1024: h1, else h2
//   bar    : [512 words] u32            @ 1835008   (2 KB)  monotonic barrier
//   h2s    : [512 t][64 b][1024 u] f16  @ 2064384   (64 MB)
//
// Block (256 = 2 m x 128 cg): M-half m (rows m*32..+32), col-group cg
// (units cg*8..+8 of BOTH layers). Combined col C = cg*32 + cb*16 + g*4 + j
// <-> gate-row g*1024 + cg*8 + cb*4 + j.
// Wave w (12/block): layer = w<4 ? 0 : 1, K-chunk kc = w<4 ? w : w-4 (256
// halfs); covers both 16-col blocks cb=0,1 (B in REGISTERS, 64 VGPR/wave;
// A loaded once, used twice). C-tiles -> LDS -> cross-wave K-reduction by
// owner threads (waves 0-3: layer0 cells, 4-7: layer1 cells).
//
// NO cache maintenance anywhere (R3-R6 showed any waited L2 inv costs
// ~14 us/iter regardless of count): h stores AND loads are agent-scope
// relaxed atomics (write-through / L2-bypass read at the L3 coherence
// point); x/tableV/weights plain-cached, never invalidated. Barrier =
// monotonic fire-and-forget adds + leader polls, zero cache ops.
// bar words (64-B spaced): grp[g]@g*16, root@128, rel[g]@144+g*16.

typedef _Float16 v8h __attribute__((ext_vector_type(8)));
typedef float v4f __attribute__((ext_vector_type(4)));
typedef _Float16 h2v __attribute__((ext_vector_type(2)));
typedef unsigned long long u64t;

__device__ __forceinline__ float sigf(float x) {
  return 1.0f / (1.0f + __expf(-x));
}

// 16-B h-read via two 8-B agent-scope relaxed atomic loads (L2-bypass,
// reads the coherence point; compiler tracks vmcnt + pipelines normally).
__device__ __forceinline__ v8h ld16(const _Float16* p) {
  u64t lo = __hip_atomic_load((const u64t*)p, __ATOMIC_RELAXED,
                              __HIP_MEMORY_SCOPE_AGENT);
  u64t hi = __hip_atomic_load(((const u64t*)p) + 1, __ATOMIC_RELAXED,
                              __HIP_MEMORY_SCOPE_AGENT);
  ulonglong2 t;
  t.x = lo;
  t.y = hi;
  return __builtin_bit_cast(v8h, t);
}

// ---------------------------------------------------------------- prep ----
__global__ __launch_bounds__(256) void prep_kernel(
    const float* __restrict__ emb, const float* __restrict__ w_ih0,
    const float* __restrict__ b_ih0, const float* __restrict__ b_hh0,
    const float* __restrict__ fc_w, _Float16* __restrict__ tableV,
    _Float16* __restrict__ fcwT, unsigned* __restrict__ zbuf,
    unsigned* __restrict__ bar) {
  const int blk = blockIdx.x, tid = threadIdx.x;
  if (blk < 2048) {
    // tableV[v][C] = emb[v]·w_ih0[row(C)] + b_ih0[row] + b_hh0[row]
    const int C = blk * 2 + (tid >> 7);
    const int v = tid & 127;
    const int row =
        ((C >> 2) & 3) * 1024 + (C >> 5) * 8 + ((C >> 4) & 1) * 4 + (C & 3);
    float acc = b_ih0[row] + b_hh0[row];
    const float* er = emb + v * 512;
    const float* wr = w_ih0 + row * 512;
#pragma unroll 4
    for (int k = 0; k < 512; ++k) acc = fmaf(er[k], wr[k], acc);
    tableV[v * 4096 + C] = (_Float16)acc;
  } else if (blk < 2560) {
    const int idx = (blk - 2048) * 256 + tid;   // [0, 131072)
    const int v = idx & 127, k = idx >> 7;
    fcwT[k * 128 + v] = (_Float16)fc_w[v * 1024 + k];
  } else if (blk < 2592) {
    // zero hcat (both ping-pong buffers): 131072 dwords over 32 blocks
    const int idx = (blk - 2560) * 256 + tid;
#pragma unroll
    for (int q = 0; q < 16; ++q) zbuf[idx * 16 + q] = 0u;
  } else {
    for (int i = tid; i < 512; i += 256) bar[i] = 0u;
  }
}

// ------------------------------------------------------------ recurrent ----
__global__ __launch_bounds__(768, 1) void lstm_mfma(
    const int* __restrict__ x, const _Float16* __restrict__ tableV,
    const float* __restrict__ w_hh0, const float* __restrict__ w_ih1,
    const float* __restrict__ w_hh1, const float* __restrict__ b_ih1,
    const float* __restrict__ b_hh1, _Float16* __restrict__ hcat,
    _Float16* __restrict__ h2s, unsigned* __restrict__ bar) {
  __shared__ float zs[12 * 2 * 32 * 17];   // [wave][cb][row32][col16+1] 52 KB

  const int tid = threadIdx.x, blk = blockIdx.x;
  const int w = tid >> 6, l = tid & 63;
  const int lane16 = l & 15, quad = l >> 4;
  const int m = blk & 1, cg = blk >> 1;
  const int kc = (w < 4) ? w : (w - 4);

  // --- stage B-fragments into REGISTERS (once) ---
  // lane16 = local col c: gate g = c>>2, unit j = c&3; per cb: 8 kk x v8h.
  v8h breg0[8], breg1[8];
  {
    const int g = lane16 >> 2, j = lane16 & 3;
    const float* Wsrc;
    int kbase;
    if (w < 4) {
      Wsrc = w_hh0;
      kbase = kc * 256;
    } else {
      const int kcomb = kc * 256;
      if (kcomb < 1024) {
        Wsrc = w_ih1;
        kbase = kcomb;
      } else {
        Wsrc = w_hh1;
        kbase = kcomb - 1024;
      }
    }
#pragma unroll
    for (int cb = 0; cb < 2; ++cb) {
      const int row = g * 1024 + cg * 8 + cb * 4 + j;
      const float* rp = Wsrc + row * 1024 + kbase + quad * 8;
#pragma unroll
      for (int kk = 0; kk < 8; ++kk) {
        const float4 f0 = *(const float4*)(rp + kk * 32);
        const float4 f1 = *(const float4*)(rp + kk * 32 + 4);
        v8h b;
        b[0] = (_Float16)f0.x; b[1] = (_Float16)f0.y;
        b[2] = (_Float16)f0.z; b[3] = (_Float16)f0.w;
        b[4] = (_Float16)f1.x; b[5] = (_Float16)f1.y;
        b[6] = (_Float16)f1.z; b[7] = (_Float16)f1.w;
        if (cb == 0) breg0[kk] = b; else breg1[kk] = b;
      }
    }
  }

  // --- elementwise-owner constants ---
  // waves 0-3: layer0 cells; waves 4-7: layer1 cells.
  // lane: j = l&7 (unit within cg's 8), b_loc = (w&3)*8 + (l>>3).
  const int oj = l & 7, ojj = l & 3, ocb = (l >> 2) & 1;
  const int ob = (w & 3) * 8 + (l >> 3);
  const int obg = m * 32 + ob;
  float bias[4] = {0.f, 0.f, 0.f, 0.f};
  if (w >= 4 && w < 8) {
#pragma unroll
    for (int g = 0; g < 4; ++g) {
      const int row = g * 1024 + cg * 8 + ocb * 4 + ojj;
      bias[g] = b_ih1[row] + b_hh1[row];
    }
  }
  _Float16 tvh[4] = {0, 0, 0, 0};
  if (w < 4) {
    const int xv = x[obg * 512];
#pragma unroll
    for (int g = 0; g < 4; ++g)
      tvh[g] = tableV[xv * 4096 + cg * 32 + ocb * 16 + g * 4 + ojj];
  }

  float cst = 0.0f;
  const int gq = blk & 7;   // barrier group

  for (int it = 0; it <= 512; ++it) {
    const _Float16* hr = hcat + (it & 1) * 131072;      // [64][2048]
    _Float16* hw = hcat + ((it + 1) & 1) * 131072;

    v4f a00 = {0, 0, 0, 0}, a01 = {0, 0, 0, 0};
    v4f a10 = {0, 0, 0, 0}, a11 = {0, 0, 0, 0};
    const bool active = (w < 4) ? (it < 512) : (it >= 1);
    if (active) {
      // A: rows m*32 + mt*16 + lane16, halfs kc*256 + kk*32 + quad*8
      const _Float16* a0p = hr + (m * 32 + lane16) * 2048 + kc * 256 + quad * 8;
      const _Float16* a1p = a0p + 16 * 2048;
      v8h A0[8], A1[8];
#pragma unroll
      for (int kk = 0; kk < 8; ++kk) A0[kk] = ld16(a0p + kk * 32);
#pragma unroll
      for (int kk = 0; kk < 8; ++kk) A1[kk] = ld16(a1p + kk * 32);
#pragma unroll
      for (int kk = 0; kk < 8; ++kk) {
        a00 = __builtin_amdgcn_mfma_f32_16x16x32_f16(A0[kk], breg0[kk], a00, 0, 0, 0);
        a10 = __builtin_amdgcn_mfma_f32_16x16x32_f16(A0[kk], breg1[kk], a10, 0, 0, 0);
      }
#pragma unroll
      for (int kk = 0; kk < 8; ++kk) {
        a01 = __builtin_amdgcn_mfma_f32_16x16x32_f16(A1[kk], breg0[kk], a01, 0, 0, 0);
        a11 = __builtin_amdgcn_mfma_f32_16x16x32_f16(A1[kk], breg1[kk], a11, 0, 0, 0);
      }
    }

    // C-tiles -> LDS (C layout: row = quad*4+r, col = lane16)
#pragma unroll
    for (int r = 0; r < 4; ++r) {
      const int rw0 = quad * 4 + r, rw1 = 16 + quad * 4 + r;
      zs[((w * 2 + 0) * 32 + rw0) * 17 + lane16] = a00[r];
      zs[((w * 2 + 0) * 32 + rw1) * 17 + lane16] = a01[r];
      zs[((w * 2 + 1) * 32 + rw0) * 17 + lane16] = a10[r];
      zs[((w * 2 + 1) * 32 + rw1) * 17 + lane16] = a11[r];
    }
    __syncthreads();

    // owner reduction + cell update
    const bool do0 = (w < 4) && (it < 512);
    const bool do1 = (w >= 4 && w < 8) && (it >= 1);
    if (do0 || do1) {
      float z[4];
      if (do0) {
#pragma unroll
        for (int g = 0; g < 4; ++g) {
          float s = (float)tvh[g];
#pragma unroll
          for (int wv = 0; wv < 4; ++wv)
            s += zs[((wv * 2 + ocb) * 32 + ob) * 17 + g * 4 + ojj];
          z[g] = s;
        }
      } else {
#pragma unroll
        for (int g = 0; g < 4; ++g) {
          float s = bias[g];
#pragma unroll
          for (int wv = 4; wv < 12; ++wv)
            s += zs[((wv * 2 + ocb) * 32 + ob) * 17 + g * 4 + ojj];
          z[g] = s;
        }
      }
      const float ig = sigf(z[0]), fg = sigf(z[1]);
      const float gg = tanhf(z[2]), og = sigf(z[3]);
      cst = fg * cst + ig * gg;
      const float hv = og * tanhf(cst);

      // pack 8 unit-lanes (same b) -> two 8-B stores (lanes oj==0, oj==4)
      const unsigned hu =
          (unsigned)__builtin_bit_cast(unsigned short, (_Float16)hv);
      const unsigned p1 = (unsigned)__shfl_xor((int)hu, 1, 64);
      const unsigned lo = (oj & 1) ? ((p1 & 0xffffu) | (hu << 16))
                                   : ((hu & 0xffffu) | (p1 << 16));
      const unsigned p2 = (unsigned)__shfl_xor((int)lo, 2, 64);
      if ((oj & 3) == 0) {
        const u64t val = (u64t)lo | ((u64t)p2 << 32);
        if (do0) {
          __hip_atomic_store((u64t*)(hw + obg * 2048 + cg * 8 + oj), val,
                             __ATOMIC_RELAXED, __HIP_MEMORY_SCOPE_AGENT);
        } else {
          __hip_atomic_store((u64t*)(hw + obg * 2048 + 1024 + cg * 8 + oj),
                             val, __ATOMIC_RELAXED, __HIP_MEMORY_SCOPE_AGENT);
          // h2s read only by the next kernel: plain cached store is fine
          *(u64t*)(h2s + ((it - 1) * 64 + obg) * 1024 + cg * 8 + oj) = val;
        }
      }
    }

    // prefetch next step's xin0 gather (tableV constant, L1-hot: no invs)
    if (w < 4 && it + 1 < 512) {
      const int xv = x[obg * 512 + it + 1];
#pragma unroll
      for (int g = 0; g < 4; ++g)
        tvh[g] = tableV[xv * 4096 + cg * 32 + ocb * 16 + g * 4 + ojj];
    }

    if (it < 512) {
      // ---- pure-atomic monotonic barrier (NO cache maintenance) ----
      asm volatile("s_waitcnt vmcnt(0)" ::: "memory");  // h stores at L3
      __syncthreads();
      if (tid == 0) {
        atomicAdd(&bar[gq * 16], 1u);                   // fire-and-forget
        if (blk == gq) {                                // group leader
          while (__hip_atomic_load(&bar[gq * 16], __ATOMIC_RELAXED,
                                   __HIP_MEMORY_SCOPE_AGENT) <
                 32u * (unsigned)(it + 1))
            __builtin_amdgcn_s_sleep(1);
          atomicAdd(&bar[128], 1u);
          if (blk == 0) {                               // root
            while (__hip_atomic_load(&bar[128], __ATOMIC_RELAXED,
                                     __HIP_MEMORY_SCOPE_AGENT) <
                   8u * (unsigned)(it + 1))
              __builtin_amdgcn_s_sleep(1);
#pragma unroll
            for (int xx = 0; xx < 8; ++xx)
              __hip_atomic_store(&bar[144 + xx * 16], (unsigned)(it + 1),
                                 __ATOMIC_RELAXED, __HIP_MEMORY_SCOPE_AGENT);
          }
        }
        while (__hip_atomic_load(&bar[144 + gq * 16], __ATOMIC_RELAXED,
                                 __HIP_MEMORY_SCOPE_AGENT) <
               (unsigned)(it + 1))
          __builtin_amdgcn_s_sleep(1);
      }
      __syncthreads();
    }
  }
}

// ---------------------------------------------------------------- FC ----
__global__ __launch_bounds__(256, 2) void fc_kernel(
    const _Float16* __restrict__ h2s, const _Float16* __restrict__ fcwT,
    const float* __restrict__ fc_b, float* __restrict__ out) {
  __shared__ float hl[16][1024];      // 64 KB
  const int tid = threadIdx.x;
  const int t = blockIdx.x >> 2, bs = blockIdx.x & 3;
  const int v = tid & 127, hh = tid >> 7;

  const h2v* hp = (const h2v*)h2s;
  for (int idx = tid; idx < 8192; idx += 256) {
    const int bl = idx >> 9, kp = idx & 511;
    const h2v pr = hp[(t * 64 + bs * 16 + bl) * 512 + kp];
    hl[bl][2 * kp] = (float)pr.x;
    hl[bl][2 * kp + 1] = (float)pr.y;
  }
  __syncthreads();

  float acc[8];
#pragma unroll
  for (int i = 0; i < 8; ++i) acc[i] = 0.0f;
  const int bl0 = hh * 8;
#pragma unroll 1
  for (int k4 = 0; k4 < 256; ++k4) {
    const int k = k4 * 4;
    const float w0 = (float)fcwT[(k + 0) * 128 + v];
    const float w1 = (float)fcwT[(k + 1) * 128 + v];
    const float w2 = (float)fcwT[(k + 2) * 128 + v];
    const float w3 = (float)fcwT[(k + 3) * 128 + v];
#pragma unroll
    for (int i = 0; i < 8; ++i) {
      const float4 hv = *(const float4*)&hl[bl0 + i][k];
      acc[i] += hv.x * w0 + hv.y * w1 + hv.z * w2 + hv.w * w3;
    }
  }
  const float bias = fc_b[v];
#pragma unroll
  for (int i = 0; i < 8; ++i) {
    const int bb = bs * 16 + bl0 + i;
    out[(bb * 512 + t) * 128 + v] = acc[i] + bias;
  }
}

// ------------------------------------------------------------- launch ----
extern "C" void kernel_launch(void* const* d_in, const int* in_sizes, int n_in,
                              void* d_out, int out_size, void* d_ws,
                              size_t ws_size, hipStream_t stream) {
  const int* x = (const int*)d_in[0];
  const float* emb = (const float*)d_in[1];
  const float* w_ih0 = (const float*)d_in[2];
  const float* w_hh0 = (const float*)d_in[3];
  const float* b_ih0 = (const float*)d_in[4];
  const float* b_hh0 = (const float*)d_in[5];
  const float* w_ih1 = (const float*)d_in[6];
  const float* w_hh1 = (const float*)d_in[7];
  const float* b_ih1 = (const float*)d_in[8];
  const float* b_hh1 = (const float*)d_in[9];
  const float* fc_w = (const float*)d_in[10];
  const float* fc_b = (const float*)d_in[11];
  float* out = (float*)d_out;

  char* ws = (char*)d_ws;
  _Float16* tableV = (_Float16*)(ws);
  _Float16* fcwT = (_Float16*)(ws + 1048576);
  _Float16* hcat = (_Float16*)(ws + 1310720);
  unsigned* bar = (unsigned*)(ws + 1835008);
  _Float16* h2s = (_Float16*)(ws + 2064384);
  unsigned* zb = (unsigned*)(ws + 1310720);

  prep_kernel<<<2593, 256, 0, stream>>>(emb, w_ih0, b_ih0, b_hh0, fc_w,
                                        tableV, fcwT, zb, bar);

  const _Float16* tableVc = tableV;
  _Float16* hcata = hcat;
  _Float16* h2sa = h2s;
  unsigned* bara = bar;
  void* args[] = {(void*)&x,     (void*)&tableVc, (void*)&w_hh0,
                  (void*)&w_ih1, (void*)&w_hh1,   (void*)&b_ih1,
                  (void*)&b_hh1, (void*)&hcata,   (void*)&h2sa,
                  (void*)&bara};
  hipLaunchCooperativeKernel(lstm_mfma, dim3(256), dim3(768), args, 0, stream);

  fc_kernel<<<2048, 256, 0, stream>>>(h2s, fcwT, fc_b, out);
}